// Round 7
// baseline (124.422 us; speedup 1.0000x reference)
//
#include <hip/hip_runtime.h>
#include <math.h>

#define PS     65
#define NPIX   (PS * PS)
#define NITEM  325                // 65 rows x 5 x-segments of 13 px
#define RPITCH 652                // slot-major ring pitch (>= 650 rings)
#define RSZ    (8 * RPITCH)       // 8 slots (bin wrap applied at write)

// atan(t)*(4/pi) for t in [0,1], degree-9 odd minimax, |err|<=1.3e-5
#define C0  1.2730689f
#define C1 -0.4205505f
#define C2  0.2293627f
#define C3 -0.1083947f
#define C4  0.0265281f

__global__ __launch_bounds__(384) void sift_desc_kernel(
        const float* __restrict__ img, float* __restrict__ out) {
    const int s   = blockIdx.x;     // slice index in (B, C, 8, 8) row-major
    const int tid = threadIdx.x;

    // decode slice -> (b, c, tile_i, tile_j)
    const int b   = s / 192;        // C*8*8 = 192
    const int rem = s - b * 192;
    const int c   = rem >> 6;
    const int t2  = rem & 63;
    const int pi  = t2 >> 3;
    const int pj  = t2 & 7;
    const float* src = img + ((size_t)((b * 3 + c) * 520 + pi * 65)) * 520 + pj * 65;

    __shared__ float patch[NPIX];   // 65x65 tile
    __shared__ float S[RSZ];        // slot-major rings: S[slot*RPITCH + ring]
    __shared__ float gtab[PS];      // normalized gaussian * sqrt(0.5)
    __shared__ float fin[128];
    __shared__ float redv[2];

    // phase 0: zero rings, gaussian table, stage patch
    for (int k = tid; k < RSZ; k += 384) S[k] = 0.0f;
    if (tid < PS) {
        float d = (float)(tid - 32);
        gtab[tid] = expf(-(d * d) * (1.0f / 4225.0f));  // sigma=65/sqrt2 -> 2s^2=4225
    }
    for (int p = tid; p < NPIX; p += 384) {
        int y = p / 65;
        int x = p - y * 65;
        patch[p] = src[y * 520 + x];
    }
    __syncthreads();

    // normalize gtab; fold sqrt(0.5) (the two 0.5 gradient factors, split per axis)
    if (tid < 64) {
        float v = gtab[tid] + ((tid == 0) ? gtab[64] : 0.0f);
        #pragma unroll
        for (int off = 32; off > 0; off >>= 1) v += __shfl_down(v, off);
        if (tid == 0) redv[0] = 0.70710678f / v;
    }
    __syncthreads();
    const float invZ = redv[0];
    if (tid < PS) gtab[tid] *= invZ;
    __syncthreads();

    // ---- fused pass: item = (row y, 13-px x-segment m). Each item owns rings
    // R = tid (r=0) and R = tid+325 (r=1); slot-major -> RMW bank = lane-distinct.
    // Dummy ring 329 (= item (y=0,m=4), r=1) absorbs zero-weight edge writes.
    if (tid < NITEM) {
        const int y  = tid / 5;
        const int m  = tid - 5 * y;
        const int x0 = 13 * m;
        const int base = (m > 0) ? m - 1 : 0;   // min window of this segment

        const int rowb = y * 65;
        const int rowm = (y > 0  ? y - 1 : 0)  * 65;
        const int rowp = (y < 64 ? y + 1 : 64) * 65;
        const float gy_t = gtab[y];

        float cprev = patch[rowb + ((x0 > 0) ? x0 - 1 : 0)];
        float ccur  = patch[rowb + x0];

        #pragma unroll
        for (int i = 0; i < 13; ++i) {
            const int x  = x0 + i;
            const int xn = (x < 64) ? x + 1 : 64;
            float cnext = patch[rowb + xn];
            float top = patch[rowm + x];
            float bot = patch[rowp + x];
            float G = cnext - cprev;            // 2*gx
            float H = bot - top;                // 2*gy
            float mag = sqrtf(fmaf(G, G, fmaf(H, H, 4e-10f))) * (gy_t * gtab[x]);

            // octant atan2 -> ob = atan2*(4/pi)+8 in [4,12]
            float Gx = G + 2e-10f;
            float ax = fabsf(Gx), ay = fabsf(H);
            float mn = fminf(ax, ay), mx = fmaxf(ax, ay);
            float t1 = mn * __builtin_amdgcn_rcpf(fmaxf(mx, 1e-35f));
            float ss = t1 * t1;
            float u9 = t1 * fmaf(ss, fmaf(ss, fmaf(ss, fmaf(ss, C4, C3), C2), C1), C0);
            float A  = (ay > ax) ? 2.0f - u9 : u9;
            A = (Gx < 0.0f) ? 4.0f - A : A;
            A = (H  < 0.0f) ? -A : A;
            float ob = A + 8.0f;
            float fl = truncf(ob);
            float fr = ob - fl;
            int b0 = ((int)fl) & 7;
            int b1 = (b0 + 1) & 7;
            float w1 = fr * mag;
            float w0 = mag - w1;

            // x-window weights: u = x+6; A-window a (t=u&15), B-window a-1 (t+16)
            const int u  = x + 6;
            const int a  = u >> 4;
            const int tA = u & 15;
            const float ftA = (float)tA;
            float wxA = fmaf(-fabsf(ftA - 12.5f), 1.0f / 13.0f, 1.0f);
            wxA = (a <= 3) ? wxA : 0.0f;
            float wxB = (tA <= 9 && a >= 1) ? (9.5f - ftA) * (1.0f / 13.0f) : 0.0f;
            int rB = a - 1 - base;
            rB = (rB < 0) ? 0 : rB;             // zero-weight -> harmless
            const int iA = tid + 325 * (a - base);   // a-base in {0,1}
            const int iB = tid + 325 * rB;

            S[b0 * RPITCH + iA] += w0 * wxA;
            S[b1 * RPITCH + iA] += w1 * wxA;
            S[b0 * RPITCH + iB] += w0 * wxB;
            S[b1 * RPITCH + iB] += w1 * wxB;

            cprev = ccur; ccur = cnext;
        }
    }
    __syncthreads();

    // ---- row pass: window j gathers 2-3 rings; dummy (329) pads to 3 sources.
    // ring offset within a slot-row: (5y + m) + 325*r
    if (tid < 128) {
        const int k  = tid >> 4;          // angular bin
        const int ii = (tid >> 2) & 3;    // y-window
        const int j  = tid & 3;           // x-window
        const int o0 = (j == 0) ? 0 : (j == 1) ? 325 : (j == 2) ? 327 : 328;
        const int o1 = (j == 0) ? 1 : (j == 1) ? 326 : (j == 2) ? 3   : 4;
        const int o2 = (j == 1) ? 2 : 329;
        const int kb = k * RPITCH;
        float v = 0.0f;
        #pragma unroll
        for (int t = 0; t < 26; ++t) {
            const int y = 16 * ii + t - 6;
            if (0 <= y && y <= 64) {
                const float wy = (13.0f - fabsf((float)t - 12.5f)) * (1.0f / 13.0f);
                const int rb = kb + 5 * y;
                v += wy * (S[rb + o0] + S[rb + o1] + S[rb + o2]);
            }
        }
        fin[tid] = v;
    }
    __syncthreads();

    // first L2 norm
    if (tid < 64) {
        float sq = fin[tid] * fin[tid] + fin[tid + 64] * fin[tid + 64];
        #pragma unroll
        for (int off = 32; off > 0; off >>= 1) sq += __shfl_down(sq, off);
        if (tid == 0) redv[0] = sq;
    }
    __syncthreads();
    float inv1 = 1.0f / fmaxf(sqrtf(redv[0]), 1e-12f);
    if (tid < 128) {
        fin[tid] = fminf(fin[tid] * inv1, 0.2f);   // non-negative; clip hi only
    }
    __syncthreads();

    // second L2 norm
    if (tid < 64) {
        float sq = fin[tid] * fin[tid] + fin[tid + 64] * fin[tid + 64];
        #pragma unroll
        for (int off = 32; off > 0; off >>= 1) sq += __shfl_down(sq, off);
        if (tid == 0) redv[1] = sq;
    }
    __syncthreads();
    float inv2 = 1.0f / fmaxf(sqrtf(redv[1]), 1e-12f);
    if (tid < 128) {
        out[(size_t)s * 128 + tid] = fin[tid] * inv2;
    }
}

extern "C" void kernel_launch(void* const* d_in, const int* in_sizes, int n_in,
                              void* d_out, int out_size, void* d_ws, size_t ws_size,
                              hipStream_t stream) {
    const float* img = (const float*)d_in[0];
    float* out = (float*)d_out;
    const int B = in_sizes[0] / (3 * 520 * 520);
    const int nslices = B * 192;
    sift_desc_kernel<<<nslices, 384, 0, stream>>>(img, out);
}